// Round 1
// 16980.202 us; speedup vs baseline: 1.0741x; 1.0741x over previous
//
#include <hip/hip_runtime.h>
#include <stdint.h>

typedef unsigned long long u64;
typedef uint32_t u32;

#define NB     256
#define NT     256
#define TMAX   2048
#define EPROJS 1024
#define DUNITS 512
#define EMBED  512
#define JOINT  512
#define ODIM   10000

#define N_LSTM 32          // blocks 0..31: LSTM + W_dec partial producers
#define CONS0  32          // blocks 32..254: consumers (W_out)
#define N_CONS 223
#define AGG_B  255         // block 255: score/token aggregator
#define MAGIC  0xD07ED07Eu

// workspace layout (bytes); first 32 KB zeroed by rnnt_init
#define WS_Y    0          // float[2][512]   y state, parity-buffered
#define WS_U    4096       // float[2][512]   u accumulators, parity-buffered
#define WS_PK   8192       // u64[4][224]     consumer packs, 4-deep ring
#define WS_SA   15360      // u64[4][224]     consumer sum-exp, 4-deep ring
#define WS_DN   22528      // u32[256]        setup-done flags
#define WS_CNT  23552      // u32 epoch-counter replicas [8] @ 128B stride
#define WS_HP   32768      // float[2048][512] h_proj  (4 MB)

__device__ __forceinline__ float aloadf(const float* p){
  return __hip_atomic_load(p, __ATOMIC_RELAXED, __HIP_MEMORY_SCOPE_AGENT);
}
__device__ __forceinline__ void astoref(float* p, float v){
  __hip_atomic_store(p, v, __ATOMIC_RELAXED, __HIP_MEMORY_SCOPE_AGENT);
}
__device__ __forceinline__ u64 aloadu64(const u64* p){
  return __hip_atomic_load(p, __ATOMIC_RELAXED, __HIP_MEMORY_SCOPE_AGENT);
}
__device__ __forceinline__ void astoreu64(u64* p, u64 v){
  __hip_atomic_store(p, v, __ATOMIC_RELAXED, __HIP_MEMORY_SCOPE_AGENT);
}
__device__ __forceinline__ u32 aloadu32(const u32* p){
  return __hip_atomic_load(p, __ATOMIC_RELAXED, __HIP_MEMORY_SCOPE_AGENT);
}
__device__ __forceinline__ void astoreu32(u32* p, u32 v){
  __hip_atomic_store(p, v, __ATOMIC_RELAXED, __HIP_MEMORY_SCOPE_AGENT);
}

__device__ __forceinline__ u32 ordbits(float f){
  u32 u = __float_as_uint(f);
  return (u & 0x80000000u) ? ~u : (u | 0x80000000u);
}
__device__ __forceinline__ float unordbits(u32 o){
  u32 u = (o & 0x80000000u) ? (o & 0x7fffffffu) : ~o;
  return __uint_as_float(u);
}
__device__ __forceinline__ float sigmoidf_(float x){ return 1.0f/(1.0f+expf(-x)); }

__device__ __forceinline__ float wredsum(float v){
  #pragma unroll
  for (int o=32;o>0;o>>=1) v += __shfl_xor(v, o);
  return v;
}
__device__ __forceinline__ u64 wredmax64(u64 v){
  #pragma unroll
  for (int o=32;o>0;o>>=1){ u64 x = __shfl_xor(v, o); v = (x>v)?x:v; }
  return v;
}

#define LOAD8(dst, baseptr) { const float4* _p=(const float4*)(baseptr); \
  float4 _a=_p[0], _b=_p[1]; \
  dst[0]=_a.x; dst[1]=_a.y; dst[2]=_a.z; dst[3]=_a.w; \
  dst[4]=_b.x; dst[5]=_b.y; dst[6]=_b.z; dst[7]=_b.w; }

#define LDS8(dst, base) { float4 _a=*(const float4*)(base); \
  float4 _b=*(const float4*)((base)+4); \
  dst[0]=_a.x; dst[1]=_a.y; dst[2]=_a.z; dst[3]=_a.w; \
  dst[4]=_b.x; dst[5]=_b.y; dst[6]=_b.z; dst[7]=_b.w; }

__global__ void rnnt_init(char* ws){
  // zero the 32 KB control region (state buffers, rings, flags, counters)
  u32* p = (u32*)ws;
  for (int i = threadIdx.x; i < 8192; i += blockDim.x) p[i] = 0u;
}

__global__ void __launch_bounds__(NT, 1)
rnnt_decode(const float* __restrict__ h,    const float* __restrict__ embed,
            const float* __restrict__ W_ih, const float* __restrict__ W_hh,
            const float* __restrict__ b_ih, const float* __restrict__ b_hh,
            const float* __restrict__ W_enc,const float* __restrict__ b_enc,
            const float* __restrict__ W_dec,const float* __restrict__ W_out,
            const float* __restrict__ b_out,
            float* __restrict__ out, char* __restrict__ ws)
{
  const int b    = blockIdx.x;
  const int tid  = threadIdx.x;
  const int lane = tid & 63;
  const int w    = tid >> 6;

  float* ybuf = (float*)(ws + WS_Y);
  float* ubuf = (float*)(ws + WS_U);
  u64*  pkall = (u64*)(ws + WS_PK);
  u64*  saall = (u64*)(ws + WS_SA);
  u32*  done  = (u32*)(ws + WS_DN);
  u32*  cnt   = (u32*)(ws + WS_CNT);
  float* hp   = (float*)(ws + WS_HP);

  __shared__ float smem[8192];                 // 32 KB, multi-purpose
  float* PL = smem;                            // [64][68] partial sums
  float* EL = &smem[4416];                     // e row   (512)
  float* YL = &smem[4928];                     // y       (512)
  float* ZL = &smem[5440];                     // z       (512)
  float* GL = &smem[5952];                     // gates   (64)
  u64*   R64= (u64*)&smem[6016];               // 4 u64 reduce slots
  float* RF = &smem[6024];                     // 4 float reduce slots
  float* YO = &smem[6032];                     // fresh own-y (16)

  // ================= setup: hp = h @ W_enc^T + b_enc (rows 8b..8b+7) =========
  {
    float (*lds_h)[EPROJS] = (float(*)[EPROJS])smem;
    #pragma unroll
    for (int r=0;r<8;r++){
      const float4 hv = *(const float4*)(h + (size_t)(8*b + r)*EPROJS + tid*4);
      *(float4*)&lds_h[r][tid*4] = hv;
    }
    __syncthreads();
    for (int p=0;p<2;p++){
      const int j = p*NT + tid;
      float acc[8] = {0,0,0,0,0,0,0,0};
      const float4* wrow = (const float4*)(W_enc + (size_t)j*EPROJS);
      for (int k4=0;k4<EPROJS/4;k4++){
        const float4 wv = wrow[k4];
        #pragma unroll
        for (int t8=0;t8<8;t8++){
          const float4 hv = *(const float4*)&lds_h[t8][k4*4];
          acc[t8] = fmaf(wv.x,hv.x, fmaf(wv.y,hv.y, fmaf(wv.z,hv.z, fmaf(wv.w,hv.w, acc[t8]))));
        }
      }
      const float be = b_enc[j];
      #pragma unroll
      for (int t8=0;t8<8;t8++)
        astoref(&hp[(size_t)(8*b+t8)*JOINT + j], acc[t8] + be);
    }
    asm volatile("s_waitcnt vmcnt(0)" ::: "memory");
    if (tid==0) astoreu32(&done[b], MAGIC);
    __syncthreads();   // smem reuse fence
  }

  // ============================ role: LSTM + u-producer ======================
  if (b < N_LSTM){
    const int d = b;
    float wih[16][8], whh[16][8];
    #pragma unroll
    for (int q=0;q<16;q++){
      const int gr = w*DUNITS + 16*d + q;       // wave w = gate type (i,f,g,o)
      LOAD8(wih[q], W_ih + (size_t)gr*EMBED  + lane*8);
      LOAD8(whh[q], W_hh + (size_t)gr*DUNITS + lane*8);
    }
    // W_dec column slice: this block contributes u_j += W_dec[j][16d..16d+15] @ y_own
    float wdc0[16], wdc1[16];
    {
      const float4* p0 = (const float4*)(W_dec + (size_t)(2*tid)*DUNITS   + 16*d);
      const float4* p1 = (const float4*)(W_dec + (size_t)(2*tid+1)*DUNITS + 16*d);
      #pragma unroll
      for (int k4=0;k4<4;k4++){
        const float4 a = p0[k4];
        wdc0[4*k4+0]=a.x; wdc0[4*k4+1]=a.y; wdc0[4*k4+2]=a.z; wdc0[4*k4+3]=a.w;
        const float4 c = p1[k4];
        wdc1[4*k4+0]=c.x; wdc1[4*k4+1]=c.y; wdc1[4*k4+2]=c.z; wdc1[4*k4+3]=c.w;
      }
    }
    float bias_r = 0.0f;
    if (tid < 64){
      const int gr = (tid>>4)*DUNITS + 16*d + (tid&15);
      bias_r = b_ih[gr] + b_hh[gr];
    }
    // bootstrap state -> publish epoch 1 (parity 1)
    float c_st = 0.0f, y_st = 0.0f;
    if (tid < 16){
      const int j = 16*d + tid;
      const float gi = b_ih[j]            + b_hh[j];
      const float gg = b_ih[2*DUNITS + j] + b_hh[2*DUNITS + j];
      const float go = b_ih[3*DUNITS + j] + b_hh[3*DUNITS + j];
      c_st = sigmoidf_(gi)*tanhf(gg);
      y_st = sigmoidf_(go)*tanhf(c_st);
      YO[tid] = y_st;
      astoref(&ybuf[512 + j], y_st);
    }
    __syncthreads();
    {
      float p0=0.f, p1=0.f;
      #pragma unroll
      for (int k=0;k<16;k++){ p0 = fmaf(wdc0[k], YO[k], p0); p1 = fmaf(wdc1[k], YO[k], p1); }
      atomicAdd(&ubuf[512 + 2*tid],   p0);
      atomicAdd(&ubuf[512 + 2*tid+1], p1);
    }
    asm volatile("s_waitcnt vmcnt(0)" ::: "memory");
    __syncthreads();
    if (tid < 8) atomicAdd(&cnt[tid*32], 1u);

    for (int t=0;t<TMAX;t++){
      const u32 g = (u32)(t+1);
      // --- wait epoch g published by all 32 LSTM blocks ---
      if (tid==0){ while (aloadu32(&cnt[(d&7)*32]) < 32u*g) {} }
      __syncthreads();
      // --- stage full y(g) (off critical path) ---
      {
        const u64* y64 = (const u64*)(ws + WS_Y + (g&1)*2048);
        const u64 v = aloadu64(&y64[tid]);
        YL[2*tid]   = __uint_as_float((u32)v);
        YL[2*tid+1] = __uint_as_float((u32)(v>>32));
      }
      __syncthreads();
      float y8[8]; LDS8(y8, &YL[8*lane]);
      float vp[16];                              // v = W_hh @ y
      #pragma unroll
      for (int q=0;q<16;q++){
        float a=0.f;
        #pragma unroll
        for (int k=0;k<8;k++) a = fmaf(whh[q][k], y8[k], a);
        vp[q] = a;
      }
      // --- poll packs(g), per-wave subsets, tag-embedded ---
      u64 pk = 0;
      {
        const u64* pks = pkall + (g&3)*224;
        for(;;){
          pk = (tid < N_CONS) ? aloadu64(&pks[tid]) : 0;
          const int ok = (tid < N_CONS) ? ((u32)(pk>>48) >= g) : 1;
          if (__all(ok)) break;
        }
      }
      { u64 m = wredmax64(pk); if (lane==0) R64[w]=m; }
      __syncthreads();
      u64 best = R64[0];
      #pragma unroll
      for (int i=1;i<4;i++){ const u64 x=R64[i]; best = (x>best)?x:best; }
      const int pred = (int)((~(u32)best) & 0xFFFFu);
      const int emitted = (pred != 0);
      // recycle the just-consumed u parity buffer for epoch g+2
      if (tid < 16) astoref(&ubuf[(g&1)*512 + 16*d + tid], 0.0f);
      // --- stage embedding row ---
      {
        const float2 ev = *(const float2*)(embed + (size_t)pred*EMBED + 2*tid);
        EL[2*tid] = ev.x; EL[2*tid+1] = ev.y;
      }
      __syncthreads();
      float e8[8]; LDS8(e8, &EL[8*lane]);
      #pragma unroll
      for (int q=0;q<16;q++){
        float a = vp[q];
        #pragma unroll
        for (int k=0;k<8;k++) a = fmaf(wih[q][k], e8[k], a);
        PL[(w*16+q)*68 + lane] = a;
      }
      __syncthreads();
      if (tid < 64){
        const float* row = &PL[tid*68];
        float s = bias_r;
        #pragma unroll
        for (int k4=0;k4<16;k4++){
          const float4 v4 = *(const float4*)&row[4*k4];
          s += v4.x + v4.y + v4.z + v4.w;
        }
        GL[tid] = s;
      }
      __syncthreads();
      if (tid < 16){
        const float gi=GL[tid], gf=GL[16+tid], gg=GL[32+tid], go=GL[48+tid];
        const float cn = sigmoidf_(gf)*c_st + sigmoidf_(gi)*tanhf(gg);
        const float yn = sigmoidf_(go)*tanhf(cn);
        if (emitted){ c_st = cn; y_st = yn; }
        YO[tid] = y_st;
        astoref(&ybuf[((g+1)&1)*512 + 16*d + tid], y_st);
      }
      __syncthreads();
      if (t < TMAX-1){
        float p0=0.f, p1=0.f;
        #pragma unroll
        for (int k=0;k<16;k++){ p0 = fmaf(wdc0[k], YO[k], p0); p1 = fmaf(wdc1[k], YO[k], p1); }
        float* up = &ubuf[((g+1)&1)*512];
        atomicAdd(&up[2*tid],   p0);
        atomicAdd(&up[2*tid+1], p1);
      }
      asm volatile("s_waitcnt vmcnt(0)" ::: "memory");
      __syncthreads();
      if (t < TMAX-1 && tid < 8) atomicAdd(&cnt[tid*32], 1u);
    }
  }
  // ============================ role: CONSUMER ===============================
  else if (b < AGG_B){
    const int cb = b - CONS0;
    int rowstart, rowcnt;
    if (cb < 188){ rowstart = cb*45;                 rowcnt = 45; }
    else         { rowstart = 8460 + (cb-188)*44;    rowcnt = 44; }
    float wout[12][8];
    #pragma unroll
    for (int q=0;q<12;q++){
      const int s = 12*w + q;
      if (s < rowcnt){
        LOAD8(wout[q], W_out + (size_t)(rowstart+s)*JOINT + lane*8);
      } else {
        #pragma unroll
        for (int k=0;k<8;k++) wout[q][k]=0.f;
      }
    }
    float my_bo = 0.f; int my_row = 0; bool my_val = false;
    if (tid < rowcnt){ my_val = true; my_row = rowstart + tid; my_bo = b_out[my_row]; }

    // wait for all hp writers (per-wave subsets)
    for(;;){
      const u32 dv = aloadu32(&done[tid]);
      if (__all(dv == MAGIC)) break;
    }
    __syncthreads();

    const u32* cp = &cnt[(cb&7)*32];
    for (int t=0;t<TMAX;t++){
      const u32 g = (u32)(t+1);
      // prefetch hp row t before the wait
      const float h0 = aloadf(&hp[(size_t)t*JOINT + 2*tid]);
      const float h1 = aloadf(&hp[(size_t)t*JOINT + 2*tid + 1]);
      if (tid==0){ while (aloadu32(cp) < 32u*g) {} }
      __syncthreads();
      // read finished u(g) once
      const u64 uv = aloadu64(&((const u64*)(ws + WS_U + (g&1)*2048))[tid]);
      const float u0 = __uint_as_float((u32)uv);
      const float u1 = __uint_as_float((u32)(uv>>32));
      ZL[2*tid]   = tanhf(h0 + u0);
      ZL[2*tid+1] = tanhf(h1 + u1);
      __syncthreads();
      float z8[8]; LDS8(z8, &ZL[8*lane]);
      #pragma unroll
      for (int q=0;q<12;q++){
        float a=0.f;
        #pragma unroll
        for (int k=0;k<8;k++) a = fmaf(wout[q][k], z8[k], a);
        PL[(12*w+q)*68 + lane] = a;
      }
      __syncthreads();
      u64 key = 0; float lg = 0.f;
      if (tid < 48){
        const float* row = &PL[tid*68];
        float s = my_bo;
        #pragma unroll
        for (int k4=0;k4<16;k4++){
          const float4 v4 = *(const float4*)&row[4*k4];
          s += v4.x + v4.y + v4.z + v4.w;
        }
        lg = s;
        if (my_val) key = ((u64)ordbits(lg)<<16) | (u64)(0xFFFFu & ~(u32)my_row);
      }
      if (w == 0){
        const u64 bk = wredmax64(key);
        const float mw = unordbits((u32)(bk>>16));
        const float e  = my_val ? __expf(lg - mw) : 0.f;
        const float sw = wredsum(e);
        if (lane == 0){
          astoreu64(&saall[(g&3)*224 + cb], ((u64)g<<32) | (u64)__float_as_uint(sw));
          astoreu64(&pkall[(g&3)*224 + cb], ((u64)g<<48) | bk);
        }
      }
      // PL/ZL reuse is protected by the next iteration's post-poll barrier
    }
  }
  // ============================ role: AGGREGATOR =============================
  else {
    float score = 0.0f;
    for (int t=0;t<TMAX;t++){
      const u32 g = (u32)(t+1);
      const u64* pks = pkall + (g&3)*224;
      const u64* sas = saall + (g&3)*224;
      u64 pk=0, sa=0;
      for(;;){
        if (tid < N_CONS){ pk = aloadu64(&pks[tid]); sa = aloadu64(&sas[tid]); }
        const int ok = (tid < N_CONS) ? (((u32)(pk>>48) >= g) & ((u32)(sa>>32) >= g)) : 1;
        if (__all(ok)) break;
      }
      { u64 m = wredmax64(pk); if (lane==0) R64[w]=m; }
      __syncthreads();
      u64 best = R64[0];
      #pragma unroll
      for (int i=1;i<4;i++){ const u64 x=R64[i]; best = (x>best)?x:best; }
      const float mstar = unordbits((u32)(best>>16));
      float term = (tid < N_CONS) ?
        __uint_as_float((u32)sa) * __expf(unordbits((u32)(pk>>16)) - mstar) : 0.f;
      term = wredsum(term);
      if (lane==0) RF[w] = term;
      __syncthreads();
      if (tid==0){
        const float S = RF[0]+RF[1]+RF[2]+RF[3];
        const int pred = (int)((~(u32)best) & 0xFFFFu);
        if (pred != 0) score += -logf(S);
        out[t] = (float)pred;
      }
      __syncthreads();   // protect R64/RF for next iteration
    }
    if (tid==0) out[TMAX] = score;
  }
}

extern "C" void kernel_launch(void* const* d_in, const int* in_sizes, int n_in,
                              void* d_out, int out_size, void* d_ws, size_t ws_size,
                              hipStream_t stream)
{
  const float* h     = (const float*)d_in[0];
  const float* embed = (const float*)d_in[1];
  const float* W_ih  = (const float*)d_in[2];
  const float* W_hh  = (const float*)d_in[3];
  const float* b_ih  = (const float*)d_in[4];
  const float* b_hh  = (const float*)d_in[5];
  const float* W_enc = (const float*)d_in[6];
  const float* b_enc = (const float*)d_in[7];
  const float* W_dec = (const float*)d_in[8];
  const float* W_out = (const float*)d_in[9];
  const float* b_out = (const float*)d_in[10];
  float* out = (float*)d_out;
  char* ws = (char*)d_ws;

  hipLaunchKernelGGL(rnnt_init, dim3(1), dim3(NT), 0, stream, ws);
  hipLaunchKernelGGL(rnnt_decode, dim3(NB), dim3(NT), 0, stream,
                     h, embed, W_ih, W_hh, b_ih, b_hh, W_enc, b_enc, W_dec, W_out, b_out,
                     out, ws);
}